// Round 15
// baseline (8421.915 us; speedup 1.0000x reference)
//
#include <hip/hip_runtime.h>
#include <stdint.h>

#define TSEQ 1024
#define H 256
#define H3 768
#define NV 50000
#define NBLK 256
#define NTHR 512
#define RPB 196            // 256 * 196 = 50176 >= 50000
#define SOS_TOK 2
#define SPIN_LIM (1 << 20)
#define NEB_L 64           // k_enc launched blocks
#define NEW 4              // encoder workers
#define EEL 64             // h-elements per worker
#define EROWS 192          // W_hh rows per worker (3*EEL)

// ---- workspace layout (bytes) ----
#define WS_SALT   0                          // u32, bumped by k_init every launch
#define WS_DISP   64                         // u32 table-work dispenser
#define WS_ROSTER 128                        // u32[8] XCD roster counters, 64B stride
#define WS_VERD   832                        // u64[4] handshake verdicts (LLC)
#define WS_HENC   1024                       // u64[2][256] packed h words
#define WS_PMX    8192                       // u64[2][256] packed decoder gate words
#define WS_REC    16384                      // u64[2][256][4] (gh0,gh1,gh2,bsum)
#define WS_EHL2   32768                      // u64[2][256] intra-XCD L2 exchange region
#define WS_GIENC  65536                      // float[1024*768] = 3MB
#define WS_TABLE  (65536 + TSEQ * H3 * 4)
#define TABLE_BYTES ((size_t)NV * H3 * 4)

using u64 = unsigned long long;

// relaxed agent-scope atomics: straight to LLC, no wbl2/inv fences
__device__ __forceinline__ void awr(u64* p, u64 v) {
  __hip_atomic_store(p, v, __ATOMIC_RELAXED, __HIP_MEMORY_SCOPE_AGENT);
}
__device__ __forceinline__ u64 ard(u64* p) {
  return __hip_atomic_load(p, __ATOMIC_RELAXED, __HIP_MEMORY_SCOPE_AGENT);
}
__device__ __forceinline__ unsigned ard32(unsigned* p) {
  return __hip_atomic_load(p, __ATOMIC_RELAXED, __HIP_MEMORY_SCOPE_AGENT);
}
__device__ __forceinline__ u64 pkf(unsigned tg, float f) {
  return ((u64)tg << 32) | (u64)__float_as_uint(f);
}
__device__ __forceinline__ u64 pku(unsigned tg, unsigned v) {
  return ((u64)tg << 32) | (u64)v;
}
__device__ __forceinline__ float upf(u64 w) { return __uint_as_float((unsigned)w); }
__device__ __forceinline__ unsigned tagof(u64 w) { return (unsigned)(w >> 32); }

// ---- intra-XCD L2 transport (encoder) ----
__device__ __forceinline__ void wgst(u64* p, u64 v) {
  __hip_atomic_store(p, v, __ATOMIC_RELAXED, __HIP_MEMORY_SCOPE_WORKGROUP);
}
__device__ __forceinline__ u64 wgld(u64* p) {
  u64 v;
  asm volatile("global_atomic_add_x2 %0, %1, %2, off sc0\n\ts_waitcnt vmcnt(0)"
               : "=v"(v) : "v"(p), "v"(0ull) : "memory");
  return v;
}

// explicit AGPR residency
__device__ __forceinline__ void agpr_w(float& dst, float v) {
  asm volatile("v_accvgpr_write_b32 %0, %1" : "=a"(dst) : "v"(v));
}
__device__ __forceinline__ float agpr_r(float src) {
  float v;
  asm volatile("v_accvgpr_read_b32 %0, %1" : "=v"(v) : "a"(src));
  return v;
}

// ---- init ----
extern "C" __global__ void k_init(char* ws) {
  if (threadIdx.x == 0) {
    unsigned* s = (unsigned*)(ws + WS_SALT);
    *s = *s + 1u;
    *(unsigned*)(ws + WS_DISP) = 0u;
    for (int i = 0; i < 8; ++i) *(unsigned*)(ws + WS_ROSTER + i * 64) = 0u;
  }
}

// ---- encoder input-transform ----
extern "C" __global__ void k_enc_gi(const int* __restrict__ x, const float* __restrict__ emb,
                                    const float* __restrict__ wih, const float* __restrict__ bih,
                                    float* __restrict__ gi) {
  int tid = threadIdx.x;
  int t0 = blockIdx.x * 16;
  __shared__ float4 se4[16][H / 4];
  float* se = (float*)se4;
  for (int idx = tid; idx < 16 * H; idx += 256) {
    int j = idx >> 8, k = idx & 255;
    se[j * H + k] = emb[(size_t)x[t0 + j] * H + k];
  }
  __syncthreads();
  for (int q = 0; q < 3; q++) {
    int r = q * H + tid;
    const float4* w4 = (const float4*)(wih + (size_t)r * H);
    float bb = bih[r];
    float a[16];
#pragma unroll
    for (int j = 0; j < 16; j++) a[j] = bb;
    for (int k = 0; k < H / 4; k++) {
      float4 wv = w4[k];
#pragma unroll
      for (int j = 0; j < 16; j++) {
        float4 ev = se4[j][k];
        a[j] += wv.x * ev.x + wv.y * ev.y + wv.z * ev.z + wv.w * ev.w;
      }
    }
#pragma unroll
    for (int j = 0; j < 16; j++) gi[(size_t)(t0 + j) * H3 + r] = a[j];
  }
}

// ---- k_enc: identical to rounds 11-14 (L2 transport verified + table fold) ----
extern "C" __global__ void __launch_bounds__(NTHR, 1)
k_enc(const float* __restrict__ enc_whh, const float* __restrict__ enc_bhh,
      const float* __restrict__ dec_emb, const float* __restrict__ dec_wih,
      const float* __restrict__ dec_bih, char* __restrict__ ws, int use_table) {
  const int b = blockIdx.x, tid = threadIdx.x;
  u64* henc = (u64*)(ws + WS_HENC);
  u64* ehl2 = (u64*)(ws + WS_EHL2);
  u64* verd = (u64*)(ws + WS_VERD);
  const float* gi_enc = (const float*)(ws + WS_GIENC);
  float* table = (float*)(ws + WS_TABLE);

  __shared__ float se[16 * H];
  __shared__ float sh_h[H];
  __shared__ float sh_ghE[EROWS];
  __shared__ int sh_xcd, sh_rank, sh_chosen, sh_u, sh_abort;
  if (tid == 0) sh_abort = 0;

  const unsigned salt = *(volatile unsigned*)(ws + WS_SALT);
  const unsigned tb32 = salt * 65536u;

  if (tid == 0) {
    unsigned x;
    asm volatile("s_getreg_b32 %0, hwreg(HW_REG_XCC_ID)" : "=s"(x));
    int myxcd = (int)(x & 7u);
    unsigned* rost = (unsigned*)(ws + WS_ROSTER);
    int rank = (int)__hip_atomic_fetch_add(rost + myxcd * 16, 1u,
                                           __ATOMIC_RELAXED, __HIP_MEMORY_SCOPE_AGENT);
    long n_ = 0;
    unsigned tot = 0;
    do {
      tot = 0;
      for (int i = 0; i < 8; ++i) tot += ard32(rost + i * 16);
      if (++n_ > 2000000L) break;
      __builtin_amdgcn_s_sleep(1);
    } while (tot < (unsigned)NEB_L);
    int chosen = -1;
    for (int i = 0; i < 8; ++i) {
      unsigned c = ard32(rost + i * 16);
      if (chosen < 0 && c >= (unsigned)NEW) chosen = i;
    }
    sh_xcd = myxcd; sh_rank = rank; sh_chosen = chosen;
  }
  __syncthreads();
  bool isw;
  int role;
  if (sh_chosen >= 0) { isw = (sh_xcd == sh_chosen) && (sh_rank < NEW); role = sh_rank; }
  else { isw = (b < NEW); role = b; }

  if (!isw) {
    if (!use_table) return;
    unsigned* disp = (unsigned*)(ws + WS_DISP);
    for (;;) {
      if (tid == 0)
        sh_u = (int)__hip_atomic_fetch_add(disp, 1u, __ATOMIC_RELAXED,
                                           __HIP_MEMORY_SCOPE_AGENT);
      __syncthreads();
      int u = sh_u;
      if (u >= NV / 16) return;
      int v0 = u * 16;
      for (int idx = tid; idx < 16 * H; idx += NTHR) {
        int j = idx >> 8, k2 = idx & 255;
        se[j * H + k2] = fmaxf(dec_emb[(size_t)(v0 + j) * H + k2], 0.f);
      }
      __syncthreads();
      for (int r = tid; r < H3; r += NTHR) {
        const float4* w4 = (const float4*)(dec_wih + (size_t)r * H);
        float bb = dec_bih[r];
        float a[16];
#pragma unroll
        for (int j = 0; j < 16; j++) a[j] = bb;
        for (int k = 0; k < H / 4; k++) {
          float4 wv = w4[k];
#pragma unroll
          for (int j = 0; j < 16; j++) {
            const float4 ev = ((const float4*)se)[j * (H / 4) + k];
            a[j] += wv.x * ev.x + wv.y * ev.y + wv.z * ev.z + wv.w * ev.w;
          }
        }
#pragma unroll
        for (int j = 0; j < 16; j++)
          table[(size_t)(v0 + j) * H3 + r] = a[j];
      }
      __syncthreads();
    }
  }

  const int el = role * EEL + (tid & 63);
  const int elw = role * EEL + tid;

  int okl = 1;
  for (int k = 0; k < 8 && okl; ++k) {
    unsigned wtg = tb32 + 50001u + (unsigned)k;
    if (tid < EEL) wgst(ehl2 + (size_t)(k & 1) * 256 + elw, pku(wtg, 0u));
    int lim = (k == 0) ? 6000 : 2000;
    int myok = 1;
    if (tid < H) {
      u64* pp_ = ehl2 + (size_t)(k & 1) * 256 + tid;
      u64 w = 0; int n_ = 0;
      do { w = wgld(pp_); } while (tagof(w) != wtg && ++n_ < lim);
      myok = (tagof(w) == wtg);
    }
    okl = __syncthreads_and(myok);
  }
  const unsigned tagV = tb32 + 60001u;
  if (tid == 0) awr(verd + role, pku(tagV, okl ? 0u : 1u));
  int fb = 0;
  if (tid < NEW) {
    u64 w = 0; int n_ = 0;
    do { w = ard(verd + tid); } while (tagof(w) != tagV && ++n_ < SPIN_LIM);
    fb = (tagof(w) != tagV) ? 1 : (int)(w & 1u);
  }
  const bool l2m = __syncthreads_and(fb == 0);
  u64* EX = l2m ? ehl2 : henc;

  const int p2 = tid >> 1, hf = tid & 1;
  const bool ract = (p2 < EROWS);
  const int q = p2 >> 6, ri = p2 & 63;
  const size_t grow = ract ? (size_t)(q * H + role * EEL + ri) : 0;
  float wa[128];
  {
    const float4* wp = (const float4*)(enc_whh + grow * H + hf * 128);
#pragma unroll
    for (int k = 0; k < 32; ++k) {
      float4 v = ract ? wp[k] : make_float4(0.f, 0.f, 0.f, 0.f);
      agpr_w(wa[4 * k + 0], v.x);
      agpr_w(wa[4 * k + 1], v.y);
      agpr_w(wa[4 * k + 2], v.z);
      agpr_w(wa[4 * k + 3], v.w);
    }
  }
  float be0 = 0.f, be1 = 0.f, be2 = 0.f;
  if (tid < EEL) { be0 = enc_bhh[el]; be1 = enc_bhh[H + el]; be2 = enc_bhh[2 * H + el]; }
  __syncthreads();

  float hb = 0.f;
  if (tid < EEL) {
    float g0 = gi_enc[el], g1 = gi_enc[H + el], g2 = gi_enc[2 * H + el];
    float r = 1.f / (1.f + expf(-(g0 + be0)));
    float z = 1.f / (1.f + expf(-(g1 + be1)));
    float n = tanhf(g2 + r * be2);
    hb = (1.f - z) * n;
    u64 w = pkf(tb32 + 1u, hb);
    if (l2m) wgst(EX + 256 + elw, w); else awr(EX + 256 + elw, w);
  }
  int ec = 1;
  for (int t = 1; t < TSEQ; ++t) {
    float g0 = 0.f, g1 = 0.f, g2 = 0.f;
    if (tid < EEL) {
      g0 = gi_enc[(size_t)t * H3 + el];
      g1 = gi_enc[(size_t)t * H3 + H + el];
      g2 = gi_enc[(size_t)t * H3 + 2 * H + el];
    }
    if (tid < H) {
      u64* pp_ = EX + (size_t)(ec & 1) * 256 + tid;
      u64 w = 0; int n_ = 0;
      if (l2m) { do { w = wgld(pp_); } while (tagof(w) != tb32 + (unsigned)ec && ++n_ < SPIN_LIM); }
      else     { do { w = ard(pp_); }  while (tagof(w) != tb32 + (unsigned)ec && ++n_ < SPIN_LIM); }
      if (tagof(w) != tb32 + (unsigned)ec) sh_abort = 1;
      sh_h[tid] = upf(w);
    }
    __syncthreads();
    if (sh_abort) return;
    float pcc = 0.f;
    if (ract) {
      const float4* h4 = ((const float4*)sh_h) + hf * 32;
#pragma unroll
      for (int k = 0; k < 32; ++k) {
        float4 hv = h4[k];
        pcc += agpr_r(wa[4 * k + 0]) * hv.x + agpr_r(wa[4 * k + 1]) * hv.y +
               agpr_r(wa[4 * k + 2]) * hv.z + agpr_r(wa[4 * k + 3]) * hv.w;
      }
    }
    pcc += __shfl_xor(pcc, 1);
    if (ract && hf == 0) sh_ghE[p2] = pcc;
    __syncthreads();
    ++ec;
    if (tid < EEL) {
      float r = 1.f / (1.f + expf(-(g0 + (sh_ghE[tid] + be0))));
      float z = 1.f / (1.f + expf(-(g1 + (sh_ghE[EEL + tid] + be1))));
      float n = tanhf(g2 + r * (sh_ghE[2 * EEL + tid] + be2));
      hb = (1.f - z) * n + z * hb;
      u64 w = pkf(tb32 + (unsigned)ec, hb);
      u64* d = EX + (size_t)(ec & 1) * 256 + elw;
      if (l2m) wgst(d, w); else awr(d, w);
    }
  }
  if (l2m && tid < EEL) awr(henc + elw, pkf(tb32 + (unsigned)TSEQ, hb));
}

// ---- decoder: r14 + early-issue/late-check gate & rec reads ----
extern "C" __global__ void __launch_bounds__(NTHR, 1)
k_dec(const float* __restrict__ dec_emb, const float* __restrict__ dec_wih,
      const float* __restrict__ dec_whh, const float* __restrict__ dec_bih,
      const float* __restrict__ dec_bhh, const float* __restrict__ w_out,
      const float* __restrict__ b_out, float* __restrict__ out,
      char* __restrict__ ws, int use_table) {
  const int b = blockIdx.x, tid = threadIdx.x;
  u64* henc = (u64*)(ws + WS_HENC);
  u64* pmx = (u64*)(ws + WS_PMX);
  u64* rec = (u64*)(ws + WS_REC);
  const float* table = (const float*)(ws + WS_TABLE);

  __shared__ float sh_h[H];
  __shared__ float sh_wd[3][H];
  __shared__ float sh_wi[3][H];
  __shared__ float sh_gi[H3];          // !use_table path only
  __shared__ float gh_lds[H3];
  __shared__ float sh_lg[2][RPB];
  __shared__ float sh_bout[RPB];
  __shared__ float sh_gh3[3];
  __shared__ float sh_rv[8];
  __shared__ float sh_mv[8];
  __shared__ int sh_mi[8];
  __shared__ float sh_mv2[8];
  __shared__ int sh_mi2[8];
  __shared__ float sh_sv2[8];
  __shared__ float sh_e[H];
  __shared__ int sh_abort;

  if (tid == 0) sh_abort = 0;

  for (int k = tid; k < 3 * H; k += NTHR) {
    int q = k >> 8, c = k & 255;
    sh_wd[q][c] = dec_whh[((size_t)(3 * b + q)) * H + c];
    if (!use_table) sh_wi[q][c] = dec_wih[((size_t)(3 * b + q)) * H + c];
  }
  const float bd0 = dec_bhh[3 * b], bd1 = dec_bhh[3 * b + 1], bd2 = dec_bhh[3 * b + 2];
  float bi0 = 0.f, bi1 = 0.f, bi2 = 0.f;
  if (!use_table) { bi0 = dec_bih[3 * b]; bi1 = dec_bih[3 * b + 1]; bi2 = dec_bih[3 * b + 2]; }
  const int rowbase = b * RPB;
  const int nrows = min(RPB, max(0, NV - rowbase));
  const int p = tid >> 1, hf = tid & 1;
  const bool wact = (p < nrows);
  float wa[128];
  {
    const float4* wp = (const float4*)(w_out + (size_t)(rowbase + (wact ? p : 0)) * H + hf * 128);
#pragma unroll
    for (int i = 0; i < 32; ++i) {
      float4 v = wact ? wp[i] : make_float4(0.f, 0.f, 0.f, 0.f);
      agpr_w(wa[4 * i + 0], v.x);
      agpr_w(wa[4 * i + 1], v.y);
      agpr_w(wa[4 * i + 2], v.z);
      agpr_w(wa[4 * i + 3], v.w);
    }
  }
  if (tid < RPB) sh_bout[tid] = (tid < nrows) ? b_out[rowbase + tid] : 0.f;
  const unsigned salt = *(volatile unsigned*)(ws + WS_SALT);
  const unsigned tb32 = salt * 65536u;
  const unsigned tb24 = salt * 4096u;
  __syncthreads();

  auto wave_maxidx = [&](float& mv, int& mi) {
#pragma unroll
    for (int off = 32; off >= 1; off >>= 1) {
      float ov = __shfl_xor(mv, off);
      int oi = __shfl_xor(mi, off);
      if (ov > mv || (ov == mv && oi < mi)) { mv = ov; mi = oi; }
    }
  };
  auto row3 = [&](const float(&wr)[3][H], float bb0, float bb1, float bb2, const float* vin) {
    int q = tid >> 7, i = tid & 127;
    float pp = 0.f;
    if (q < 3) pp = wr[q][2 * i] * vin[2 * i] + wr[q][2 * i + 1] * vin[2 * i + 1];
#pragma unroll
    for (int off = 32; off >= 1; off >>= 1) pp += __shfl_xor(pp, off);
    if (q < 3 && (tid & 63) == 0) sh_rv[tid >> 6] = pp;
    __syncthreads();
    if (tid == 0) {
      sh_gh3[0] = sh_rv[0] + sh_rv[1] + bb0;
      sh_gh3[1] = sh_rv[2] + sh_rv[3] + bb1;
      sh_gh3[2] = sh_rv[4] + sh_rv[5] + bb2;
    }
    __syncthreads();
  };
  auto spin_rec3 = [&](unsigned tg, float* dst) {
    if (tid < NBLK) {
      u64* pp_ = rec + (size_t)(tg & 1) * 1024 + (size_t)tid * 4;
      u64 w0 = 0, w1 = 0, w2 = 0; int n = 0; bool ok;
      do {
        w0 = ard(pp_ + 0); w1 = ard(pp_ + 1); w2 = ard(pp_ + 2);
        ok = (tagof(w0) == tg) & (tagof(w1) == tg) & (tagof(w2) == tg);
      } while (!ok && ++n < SPIN_LIM);
      if (!ok) sh_abort = 1;
      dst[3 * tid] = upf(w0); dst[3 * tid + 1] = upf(w1); dst[3 * tid + 2] = upf(w2);
    }
    __syncthreads();
  };

  // ---- gather h_enc ----
  if (tid < NBLK) {
    u64* pp_ = henc + tid;
    u64 w = 0; int n_ = 0;
    do { w = ard(pp_); } while (tagof(w) != tb32 + (unsigned)TSEQ && ++n_ < SPIN_LIM);
    if (tagof(w) != tb32 + (unsigned)TSEQ) sh_abort = 1;
    sh_h[tid] = upf(w);
  }
  __syncthreads();
  if (sh_abort) return;

  int e = TSEQ;
  // ---- bridge ----
  row3(sh_wd, bd0, bd1, bd2, sh_h);
  ++e;
  {
    unsigned tg = tb32 + (unsigned)e;
    if (tid == 0) {
      u64* d = rec + (size_t)(tg & 1) * 1024 + (size_t)b * 4;
      awr(d + 0, pkf(tg, sh_gh3[0]));
      awr(d + 1, pkf(tg, sh_gh3[1]));
      awr(d + 2, pkf(tg, sh_gh3[2]));
    }
    spin_rec3(tg, gh_lds);
    if (sh_abort) return;
  }

  int tok = SOS_TOK;
  float g0 = 0.f, g1 = 0.f, g2 = 0.f;   // per-thread gi registers (tid<256, table path)
  if (use_table) {
    if (tid < H) {
      const float* tr = table + (size_t)SOS_TOK * H3;
      g0 = tr[tid]; g1 = tr[H + tid]; g2 = tr[2 * H + tid];
    }
  } else {
    for (int j = tid; j < H; j += NTHR) sh_e[j] = fmaxf(dec_emb[(size_t)SOS_TOK * H + j], 0.f);
    __syncthreads();
    row3(sh_wi, bi0, bi1, bi2, sh_e);
    ++e;
    unsigned tg = tb32 + (unsigned)e;
    if (tid == 0) {
      u64* d = rec + (size_t)(tg & 1) * 1024 + (size_t)b * 4;
      awr(d + 0, pkf(tg, sh_gh3[0]));
      awr(d + 1, pkf(tg, sh_gh3[1]));
      awr(d + 2, pkf(tg, sh_gh3[2]));
    }
    spin_rec3(tg, sh_gi);
    if (sh_abort) return;
  }

  const int wv = tid >> 6, ln = tid & 63;
  float sv_p = 0.f, bm_p = -INFINITY, gm_p = 0.f;
  for (int t = 0; t < TSEQ; ++t) {
    const int cur = t & 1;
    // B: gru — gi from registers (table) or sh_gi (exchange); no pre-barrier needed
    if (tid < H) {
      float gir, giz, gin;
      if (use_table) { gir = g0; giz = g1; gin = g2; }
      else { gir = sh_gi[tid]; giz = sh_gi[H + tid]; gin = sh_gi[2 * H + tid]; }
      float ghr = gh_lds[tid], ghz = gh_lds[H + tid], ghn = gh_lds[2 * H + tid];
      float r = 1.f / (1.f + expf(-(gir + ghr)));
      float z = 1.f / (1.f + expf(-(giz + ghz)));
      float n = tanhf(gin + r * ghn);
      sh_h[tid] = (1.f - z) * n + z * sh_h[tid];
    }
    __syncthreads();                      // barrier 1: sh_h committed
    // C: logits + register wave-max (one barrier commits sh_lg AND sh_mv)
    float acc = 0.f;
    if (wact) {
      const float4* h4 = ((const float4*)sh_h) + hf * 32;
#pragma unroll
      for (int i = 0; i < 32; ++i) {
        float4 hv = h4[i];
        acc += agpr_r(wa[4 * i + 0]) * hv.x + agpr_r(wa[4 * i + 1]) * hv.y +
               agpr_r(wa[4 * i + 2]) * hv.z + agpr_r(wa[4 * i + 3]) * hv.w;
      }
    }
    acc += __shfl_xor(acc, 1);
    float lgv = acc + ((wact && hf == 0) ? sh_bout[p] : 0.f);
    if (wact && hf == 0) sh_lg[cur][p] = lgv;
    float mv = (wact && hf == 0) ? lgv : -INFINITY;
    int mi = (wact && hf == 0) ? (rowbase + p) : 0x7fffffff;
    wave_maxidx(mv, mi);
    if (ln == 0) { sh_mv[wv] = mv; sh_mi[wv] = mi; }
    __syncthreads();                      // barrier 2: sh_lg + sh_mv committed
    ++e;
    const unsigned tg32 = tb32 + (unsigned)e;
    const unsigned tg24 = (tb24 + (unsigned)e) & 0xFFFFFFu;
    // D: 8-way merge -> gate publish FIRST
    float bmax = sh_mv[0]; int bidx = sh_mi[0];
#pragma unroll
    for (int k = 1; k < 8; ++k)
      if (sh_mv[k] > bmax || (sh_mv[k] == bmax && sh_mi[k] < bidx)) { bmax = sh_mv[k]; bidx = sh_mi[k]; }
    if (tid == 0) {
      u64 g = ((u64)tg24 << 40) | ((u64)__float_as_uint(bmax) << 8) |
              (u64)((unsigned)(bidx - rowbase) & 0xFFu);
      awr(pmx + (size_t)(e & 1) * 256 + b, g);
    }
    // E: wave-parallel production, barrier-free (r12/r13-proven math)
    if (wv < 3) {
      float pp = 0.f;
      const float* wr = sh_wd[wv];
      int c0 = 4 * ln;
#pragma unroll
      for (int j = 0; j < 4; ++j) pp += wr[c0 + j] * sh_h[c0 + j];
#pragma unroll
      for (int off = 32; off >= 1; off >>= 1) pp += __shfl_xor(pp, off);
      if (ln == 0) {
        float bb = (wv == 0) ? bd0 : ((wv == 1) ? bd1 : bd2);
        awr(rec + (size_t)(e & 1) * 1024 + (size_t)b * 4 + wv, pkf(tg32, pp + bb));
      }
    } else if (wv == 3) {
      float s = 0.f;
#pragma unroll
      for (int j = 0; j < 4; ++j) {
        int r2 = ln + 64 * j;
        if (r2 < nrows) s += __expf(sh_lg[cur][r2] - bmax);
      }
#pragma unroll
      for (int off = 32; off >= 1; off >>= 1) s += __shfl_xor(s, off);
      if (ln == 0)
        awr(rec + (size_t)(e & 1) * 1024 + (size_t)b * 4 + 3, pkf(tg32, s));
    }
    // early-issue gate read: in flight while F runs
    u64* gpp = pmx + (size_t)(e & 1) * 256 + tid;
    u64 gw = 0;
    if (tid < NBLK) gw = ard(gpp);
    // F: deferred lse(t-1) + out row t-1 (absorbed by publish->detect slack)
    if (t > 0) {
      float c = (tid < NBLK) ? sv_p * __expf(bm_p - gm_p) : 0.f;
#pragma unroll
      for (int off = 32; off >= 1; off >>= 1) c += __shfl_xor(c, off);
      if (ln == 0) sh_sv2[wv] = c;
      __syncthreads();                    // barrier 3
      float S = 0.f;
#pragma unroll
      for (int k = 0; k < 8; ++k) S += sh_sv2[k];
      float lse = gm_p + logf(S);
      if (tid < nrows)
        out[(size_t)(t - 1) * NV + rowbase + tid] = sh_lg[cur ^ 1][tid] - lse;
    }
    // G: gate check (pre-issued) -> spin only on miss; then pre-issue rec reads
    float bm_e = -INFINITY; int ie = 0x7fffffff;
    u64 rw0 = 0, rw1 = 0, rw2 = 0, rw3 = 0;
    {
      if (tid < NBLK) {
        int n = 0;
        while ((unsigned)(gw >> 40) != tg24 && ++n < SPIN_LIM) gw = ard(gpp);
        if ((unsigned)(gw >> 40) != tg24) sh_abort = 1;
        bm_e = __uint_as_float((unsigned)((gw >> 8) & 0xFFFFFFFFu));
        ie = tid * RPB + (int)(gw & 0xFFu);
        // pre-issue rec reads: in flight during merge + table issue
        u64* rp = rec + (size_t)(e & 1) * 1024 + (size_t)tid * 4;
        rw0 = ard(rp + 0); rw1 = ard(rp + 1); rw2 = ard(rp + 2); rw3 = ard(rp + 3);
      }
      __syncthreads();                    // barrier 4
      if (sh_abort) return;
    }
    // merge argmax -> tok
    float mv2 = bm_e; int mi2 = ie;
    wave_maxidx(mv2, mi2);
    if (ln == 0) { sh_mv2[wv] = mv2; sh_mi2[wv] = mi2; }
    __syncthreads();                      // barrier 5
    float gmax = sh_mv2[0]; int gidx = sh_mi2[0];
#pragma unroll
    for (int k = 1; k < 8; ++k)
      if (sh_mv2[k] > gmax || (sh_mv2[k] == gmax && sh_mi2[k] < gidx)) { gmax = sh_mv2[k]; gidx = sh_mi2[k]; }
    tok = gidx;
    // issue next token's gi register loads (latency hidden under rec validation)
    if (use_table && t + 1 < TSEQ && tid < H) {
      const float* tr = table + (size_t)tok * H3;
      g0 = tr[tid]; g1 = tr[H + tid]; g2 = tr[2 * H + tid];
    }
    // H: validate pre-issued rec words; re-spin only on miss
    float sv = 0.f;
    if (tid < NBLK) {
      u64* rp = rec + (size_t)(e & 1) * 1024 + (size_t)tid * 4;
      bool ok = (tagof(rw0) == tg32) & (tagof(rw1) == tg32) & (tagof(rw2) == tg32) &
                (tagof(rw3) == tg32);
      int n = 0;
      while (!ok && ++n < SPIN_LIM) {
        rw0 = ard(rp + 0); rw1 = ard(rp + 1); rw2 = ard(rp + 2); rw3 = ard(rp + 3);
        ok = (tagof(rw0) == tg32) & (tagof(rw1) == tg32) & (tagof(rw2) == tg32) &
             (tagof(rw3) == tg32);
      }
      if (!ok) sh_abort = 1;
      gh_lds[3 * tid] = upf(rw0); gh_lds[3 * tid + 1] = upf(rw1); gh_lds[3 * tid + 2] = upf(rw2);
      sv = upf(rw3);
    }
    __syncthreads();                      // barrier 6
    if (sh_abort) return;
    sv_p = sv; bm_p = bm_e; gm_p = gmax;
    // !use_table: full gi exchange for next token
    if (!use_table && t + 1 < TSEQ) {
      for (int j = tid; j < H; j += NTHR) sh_e[j] = fmaxf(dec_emb[(size_t)tok * H + j], 0.f);
      __syncthreads();
      row3(sh_wi, bi0, bi1, bi2, sh_e);
      ++e;
      unsigned tgg = tb32 + (unsigned)e;
      if (tid == 0) {
        u64* d = rec + (size_t)(tgg & 1) * 1024 + (size_t)b * 4;
        awr(d + 0, pkf(tgg, sh_gh3[0]));
        awr(d + 1, pkf(tgg, sh_gh3[1]));
        awr(d + 2, pkf(tgg, sh_gh3[2]));
      }
      spin_rec3(tgg, sh_gi);
      if (sh_abort) return;
    }
  }
  // epilogue: lse + final row
  {
    float c = (tid < NBLK) ? sv_p * __expf(bm_p - gm_p) : 0.f;
#pragma unroll
    for (int off = 32; off >= 1; off >>= 1) c += __shfl_xor(c, off);
    if (ln == 0) sh_sv2[wv] = c;
    __syncthreads();
    float S = 0.f;
#pragma unroll
    for (int k = 0; k < 8; ++k) S += sh_sv2[k];
    float lse = gm_p + logf(S);
    if (tid < nrows)
      out[(size_t)(TSEQ - 1) * NV + rowbase + tid] = sh_lg[(TSEQ - 1) & 1][tid] - lse;
  }
}

extern "C" void kernel_launch(void* const* d_in, const int* in_sizes, int n_in,
                              void* d_out, int out_size, void* d_ws, size_t ws_size,
                              hipStream_t stream) {
  (void)in_sizes; (void)n_in; (void)out_size;
  const int* x = (const int*)d_in[0];
  const float* enc_emb = (const float*)d_in[1];
  const float* enc_wih = (const float*)d_in[2];
  const float* enc_whh = (const float*)d_in[3];
  const float* enc_bih = (const float*)d_in[4];
  const float* enc_bhh = (const float*)d_in[5];
  const float* dec_emb = (const float*)d_in[6];
  const float* dec_wih = (const float*)d_in[7];
  const float* dec_whh = (const float*)d_in[8];
  const float* dec_bih = (const float*)d_in[9];
  const float* dec_bhh = (const float*)d_in[10];
  const float* w_out = (const float*)d_in[11];
  const float* b_out = (const float*)d_in[12];
  float* out = (float*)d_out;
  char* ws = (char*)d_ws;

  int use_table = (ws_size >= (size_t)WS_TABLE + TABLE_BYTES) ? 1 : 0;

  k_init<<<1, 64, 0, stream>>>(ws);
  k_enc_gi<<<TSEQ / 16, 256, 0, stream>>>(x, enc_emb, enc_wih, enc_bih, (float*)(ws + WS_GIENC));
  k_enc<<<NEB_L, NTHR, 0, stream>>>(enc_whh, enc_bhh, dec_emb, dec_wih, dec_bih, ws, use_table);
  k_dec<<<NBLK, NTHR, 0, stream>>>(dec_emb, dec_wih, dec_whh, dec_bih, dec_bhh,
                                   w_out, b_out, out, ws, use_table);
}

// Round 16
// 8001.607 us; speedup vs baseline: 1.0525x; 1.0525x over previous
//
#include <hip/hip_runtime.h>
#include <stdint.h>

#define TSEQ 1024
#define H 256
#define H3 768
#define NV 50000
#define NBLK 256
#define NTHR 512
#define RPB 196            // 256 * 196 = 50176 >= 50000
#define SOS_TOK 2
#define SPIN_LIM (1 << 20)
#define NEB_L 64           // k_enc launched blocks
#define NEW 4              // encoder workers
#define EEL 64             // h-elements per worker
#define EROWS 192          // W_hh rows per worker (3*EEL)

// ---- workspace layout (bytes) ----
#define WS_SALT   0                          // u32, bumped by k_init every launch
#define WS_DISP   64                         // u32 table-work dispenser
#define WS_ROSTER 128                        // u32[8] XCD roster counters, 64B stride
#define WS_VERD   832                        // u64[4] handshake verdicts (LLC)
#define WS_HENC   1024                       // u64[2][256] packed h words
#define WS_PMX    8192                       // u64[2][256] packed decoder gate words
#define WS_REC    16384                      // u64[2][256][4] (gh0,gh1,gh2,bsum)
#define WS_EHL2   32768                      // u64[2][256] intra-XCD L2 exchange region
#define WS_GIENC  65536                      // float[1024*768] = 3MB
#define WS_TABLE  (65536 + TSEQ * H3 * 4)
#define TABLE_BYTES ((size_t)NV * H3 * 4)

using u64 = unsigned long long;

// relaxed agent-scope atomics: straight to LLC, no wbl2/inv fences
__device__ __forceinline__ void awr(u64* p, u64 v) {
  __hip_atomic_store(p, v, __ATOMIC_RELAXED, __HIP_MEMORY_SCOPE_AGENT);
}
__device__ __forceinline__ u64 ard(u64* p) {
  return __hip_atomic_load(p, __ATOMIC_RELAXED, __HIP_MEMORY_SCOPE_AGENT);
}
__device__ __forceinline__ unsigned ard32(unsigned* p) {
  return __hip_atomic_load(p, __ATOMIC_RELAXED, __HIP_MEMORY_SCOPE_AGENT);
}
__device__ __forceinline__ u64 pkf(unsigned tg, float f) {
  return ((u64)tg << 32) | (u64)__float_as_uint(f);
}
__device__ __forceinline__ u64 pku(unsigned tg, unsigned v) {
  return ((u64)tg << 32) | (u64)v;
}
__device__ __forceinline__ float upf(u64 w) { return __uint_as_float((unsigned)w); }
__device__ __forceinline__ unsigned tagof(u64 w) { return (unsigned)(w >> 32); }

// ---- intra-XCD L2 transport (encoder) ----
__device__ __forceinline__ void wgst(u64* p, u64 v) {
  __hip_atomic_store(p, v, __ATOMIC_RELAXED, __HIP_MEMORY_SCOPE_WORKGROUP);
}
__device__ __forceinline__ u64 wgld(u64* p) {
  u64 v;
  asm volatile("global_atomic_add_x2 %0, %1, %2, off sc0\n\ts_waitcnt vmcnt(0)"
               : "=v"(v) : "v"(p), "v"(0ull) : "memory");
  return v;
}

// explicit AGPR residency
__device__ __forceinline__ void agpr_w(float& dst, float v) {
  asm volatile("v_accvgpr_write_b32 %0, %1" : "=a"(dst) : "v"(v));
}
__device__ __forceinline__ float agpr_r(float src) {
  float v;
  asm volatile("v_accvgpr_read_b32 %0, %1" : "=v"(v) : "a"(src));
  return v;
}

// ---- init ----
extern "C" __global__ void k_init(char* ws) {
  if (threadIdx.x == 0) {
    unsigned* s = (unsigned*)(ws + WS_SALT);
    *s = *s + 1u;
    *(unsigned*)(ws + WS_DISP) = 0u;
    for (int i = 0; i < 8; ++i) *(unsigned*)(ws + WS_ROSTER + i * 64) = 0u;
  }
}

// ---- encoder input-transform ----
extern "C" __global__ void k_enc_gi(const int* __restrict__ x, const float* __restrict__ emb,
                                    const float* __restrict__ wih, const float* __restrict__ bih,
                                    float* __restrict__ gi) {
  int tid = threadIdx.x;
  int t0 = blockIdx.x * 16;
  __shared__ float4 se4[16][H / 4];
  float* se = (float*)se4;
  for (int idx = tid; idx < 16 * H; idx += 256) {
    int j = idx >> 8, k = idx & 255;
    se[j * H + k] = emb[(size_t)x[t0 + j] * H + k];
  }
  __syncthreads();
  for (int q = 0; q < 3; q++) {
    int r = q * H + tid;
    const float4* w4 = (const float4*)(wih + (size_t)r * H);
    float bb = bih[r];
    float a[16];
#pragma unroll
    for (int j = 0; j < 16; j++) a[j] = bb;
    for (int k = 0; k < H / 4; k++) {
      float4 wv = w4[k];
#pragma unroll
      for (int j = 0; j < 16; j++) {
        float4 ev = se4[j][k];
        a[j] += wv.x * ev.x + wv.y * ev.y + wv.z * ev.z + wv.w * ev.w;
      }
    }
#pragma unroll
    for (int j = 0; j < 16; j++) gi[(size_t)(t0 + j) * H3 + r] = a[j];
  }
}

// ---- k_enc: L2 transport verified + table fold ----
extern "C" __global__ void __launch_bounds__(NTHR, 1)
k_enc(const float* __restrict__ enc_whh, const float* __restrict__ enc_bhh,
      const float* __restrict__ dec_emb, const float* __restrict__ dec_wih,
      const float* __restrict__ dec_bih, char* __restrict__ ws, int use_table) {
  const int b = blockIdx.x, tid = threadIdx.x;
  u64* henc = (u64*)(ws + WS_HENC);
  u64* ehl2 = (u64*)(ws + WS_EHL2);
  u64* verd = (u64*)(ws + WS_VERD);
  const float* gi_enc = (const float*)(ws + WS_GIENC);
  float* table = (float*)(ws + WS_TABLE);

  __shared__ float se[16 * H];
  __shared__ float sh_h[H];
  __shared__ float sh_ghE[EROWS];
  __shared__ int sh_xcd, sh_rank, sh_chosen, sh_u, sh_abort;
  if (tid == 0) sh_abort = 0;

  const unsigned salt = *(volatile unsigned*)(ws + WS_SALT);
  const unsigned tb32 = salt * 65536u;

  if (tid == 0) {
    unsigned x;
    asm volatile("s_getreg_b32 %0, hwreg(HW_REG_XCC_ID)" : "=s"(x));
    int myxcd = (int)(x & 7u);
    unsigned* rost = (unsigned*)(ws + WS_ROSTER);
    int rank = (int)__hip_atomic_fetch_add(rost + myxcd * 16, 1u,
                                           __ATOMIC_RELAXED, __HIP_MEMORY_SCOPE_AGENT);
    long n_ = 0;
    unsigned tot = 0;
    do {
      tot = 0;
      for (int i = 0; i < 8; ++i) tot += ard32(rost + i * 16);
      if (++n_ > 2000000L) break;
      __builtin_amdgcn_s_sleep(1);
    } while (tot < (unsigned)NEB_L);
    int chosen = -1;
    for (int i = 0; i < 8; ++i) {
      unsigned c = ard32(rost + i * 16);
      if (chosen < 0 && c >= (unsigned)NEW) chosen = i;
    }
    sh_xcd = myxcd; sh_rank = rank; sh_chosen = chosen;
  }
  __syncthreads();
  bool isw;
  int role;
  if (sh_chosen >= 0) { isw = (sh_xcd == sh_chosen) && (sh_rank < NEW); role = sh_rank; }
  else { isw = (b < NEW); role = b; }

  if (!isw) {
    if (!use_table) return;
    unsigned* disp = (unsigned*)(ws + WS_DISP);
    for (;;) {
      if (tid == 0)
        sh_u = (int)__hip_atomic_fetch_add(disp, 1u, __ATOMIC_RELAXED,
                                           __HIP_MEMORY_SCOPE_AGENT);
      __syncthreads();
      int u = sh_u;
      if (u >= NV / 16) return;
      int v0 = u * 16;
      for (int idx = tid; idx < 16 * H; idx += NTHR) {
        int j = idx >> 8, k2 = idx & 255;
        se[j * H + k2] = fmaxf(dec_emb[(size_t)(v0 + j) * H + k2], 0.f);
      }
      __syncthreads();
      for (int r = tid; r < H3; r += NTHR) {
        const float4* w4 = (const float4*)(dec_wih + (size_t)r * H);
        float bb = dec_bih[r];
        float a[16];
#pragma unroll
        for (int j = 0; j < 16; j++) a[j] = bb;
        for (int k = 0; k < H / 4; k++) {
          float4 wv = w4[k];
#pragma unroll
          for (int j = 0; j < 16; j++) {
            const float4 ev = ((const float4*)se)[j * (H / 4) + k];
            a[j] += wv.x * ev.x + wv.y * ev.y + wv.z * ev.z + wv.w * ev.w;
          }
        }
#pragma unroll
        for (int j = 0; j < 16; j++)
          table[(size_t)(v0 + j) * H3 + r] = a[j];
      }
      __syncthreads();
    }
  }

  const int el = role * EEL + (tid & 63);
  const int elw = role * EEL + tid;

  int okl = 1;
  for (int k = 0; k < 8 && okl; ++k) {
    unsigned wtg = tb32 + 50001u + (unsigned)k;
    if (tid < EEL) wgst(ehl2 + (size_t)(k & 1) * 256 + elw, pku(wtg, 0u));
    int lim = (k == 0) ? 6000 : 2000;
    int myok = 1;
    if (tid < H) {
      u64* pp_ = ehl2 + (size_t)(k & 1) * 256 + tid;
      u64 w = 0; int n_ = 0;
      do { w = wgld(pp_); } while (tagof(w) != wtg && ++n_ < lim);
      myok = (tagof(w) == wtg);
    }
    okl = __syncthreads_and(myok);
  }
  const unsigned tagV = tb32 + 60001u;
  if (tid == 0) awr(verd + role, pku(tagV, okl ? 0u : 1u));
  int fb = 0;
  if (tid < NEW) {
    u64 w = 0; int n_ = 0;
    do { w = ard(verd + tid); } while (tagof(w) != tagV && ++n_ < SPIN_LIM);
    fb = (tagof(w) != tagV) ? 1 : (int)(w & 1u);
  }
  const bool l2m = __syncthreads_and(fb == 0);
  u64* EX = l2m ? ehl2 : henc;

  const int p2 = tid >> 1, hf = tid & 1;
  const bool ract = (p2 < EROWS);
  const int q = p2 >> 6, ri = p2 & 63;
  const size_t grow = ract ? (size_t)(q * H + role * EEL + ri) : 0;
  float wa[128];
  {
    const float4* wp = (const float4*)(enc_whh + grow * H + hf * 128);
#pragma unroll
    for (int k = 0; k < 32; ++k) {
      float4 v = ract ? wp[k] : make_float4(0.f, 0.f, 0.f, 0.f);
      agpr_w(wa[4 * k + 0], v.x);
      agpr_w(wa[4 * k + 1], v.y);
      agpr_w(wa[4 * k + 2], v.z);
      agpr_w(wa[4 * k + 3], v.w);
    }
  }
  float be0 = 0.f, be1 = 0.f, be2 = 0.f;
  if (tid < EEL) { be0 = enc_bhh[el]; be1 = enc_bhh[H + el]; be2 = enc_bhh[2 * H + el]; }
  __syncthreads();

  float hb = 0.f;
  if (tid < EEL) {
    float g0 = gi_enc[el], g1 = gi_enc[H + el], g2 = gi_enc[2 * H + el];
    float r = 1.f / (1.f + expf(-(g0 + be0)));
    float z = 1.f / (1.f + expf(-(g1 + be1)));
    float n = tanhf(g2 + r * be2);
    hb = (1.f - z) * n;
    u64 w = pkf(tb32 + 1u, hb);
    if (l2m) wgst(EX + 256 + elw, w); else awr(EX + 256 + elw, w);
  }
  int ec = 1;
  for (int t = 1; t < TSEQ; ++t) {
    float g0 = 0.f, g1 = 0.f, g2 = 0.f;
    if (tid < EEL) {
      g0 = gi_enc[(size_t)t * H3 + el];
      g1 = gi_enc[(size_t)t * H3 + H + el];
      g2 = gi_enc[(size_t)t * H3 + 2 * H + el];
    }
    if (tid < H) {
      u64* pp_ = EX + (size_t)(ec & 1) * 256 + tid;
      u64 w = 0; int n_ = 0;
      if (l2m) { do { w = wgld(pp_); } while (tagof(w) != tb32 + (unsigned)ec && ++n_ < SPIN_LIM); }
      else     { do { w = ard(pp_); }  while (tagof(w) != tb32 + (unsigned)ec && ++n_ < SPIN_LIM); }
      if (tagof(w) != tb32 + (unsigned)ec) sh_abort = 1;
      sh_h[tid] = upf(w);
    }
    __syncthreads();
    if (sh_abort) return;
    float pcc = 0.f;
    if (ract) {
      const float4* h4 = ((const float4*)sh_h) + hf * 32;
#pragma unroll
      for (int k = 0; k < 32; ++k) {
        float4 hv = h4[k];
        pcc += agpr_r(wa[4 * k + 0]) * hv.x + agpr_r(wa[4 * k + 1]) * hv.y +
               agpr_r(wa[4 * k + 2]) * hv.z + agpr_r(wa[4 * k + 3]) * hv.w;
      }
    }
    pcc += __shfl_xor(pcc, 1);
    if (ract && hf == 0) sh_ghE[p2] = pcc;
    __syncthreads();
    ++ec;
    if (tid < EEL) {
      float r = 1.f / (1.f + expf(-(g0 + (sh_ghE[tid] + be0))));
      float z = 1.f / (1.f + expf(-(g1 + (sh_ghE[EEL + tid] + be1))));
      float n = tanhf(g2 + r * (sh_ghE[2 * EEL + tid] + be2));
      hb = (1.f - z) * n + z * hb;
      u64 w = pkf(tb32 + (unsigned)ec, hb);
      u64* d = EX + (size_t)(ec & 1) * 256 + elw;
      if (l2m) wgst(d, w); else awr(d, w);
    }
  }
  if (l2m && tid < EEL) awr(henc + elw, pkf(tb32 + (unsigned)TSEQ, hb));
}

// ---- decoder: r14 (best measured) — register-gi + fused max + 6-barrier loop ----
extern "C" __global__ void __launch_bounds__(NTHR, 1)
k_dec(const float* __restrict__ dec_emb, const float* __restrict__ dec_wih,
      const float* __restrict__ dec_whh, const float* __restrict__ dec_bih,
      const float* __restrict__ dec_bhh, const float* __restrict__ w_out,
      const float* __restrict__ b_out, float* __restrict__ out,
      char* __restrict__ ws, int use_table) {
  const int b = blockIdx.x, tid = threadIdx.x;
  u64* henc = (u64*)(ws + WS_HENC);
  u64* pmx = (u64*)(ws + WS_PMX);
  u64* rec = (u64*)(ws + WS_REC);
  const float* table = (const float*)(ws + WS_TABLE);

  __shared__ float sh_h[H];
  __shared__ float sh_wd[3][H];
  __shared__ float sh_wi[3][H];
  __shared__ float sh_gi[H3];          // !use_table path only
  __shared__ float gh_lds[H3];
  __shared__ float sh_lg[2][RPB];
  __shared__ float sh_bout[RPB];
  __shared__ float sh_gh3[3];
  __shared__ float sh_rv[8];
  __shared__ float sh_mv[8];
  __shared__ int sh_mi[8];
  __shared__ float sh_mv2[8];
  __shared__ int sh_mi2[8];
  __shared__ float sh_sv2[8];
  __shared__ float sh_e[H];
  __shared__ int sh_abort;

  if (tid == 0) sh_abort = 0;

  for (int k = tid; k < 3 * H; k += NTHR) {
    int q = k >> 8, c = k & 255;
    sh_wd[q][c] = dec_whh[((size_t)(3 * b + q)) * H + c];
    if (!use_table) sh_wi[q][c] = dec_wih[((size_t)(3 * b + q)) * H + c];
  }
  const float bd0 = dec_bhh[3 * b], bd1 = dec_bhh[3 * b + 1], bd2 = dec_bhh[3 * b + 2];
  float bi0 = 0.f, bi1 = 0.f, bi2 = 0.f;
  if (!use_table) { bi0 = dec_bih[3 * b]; bi1 = dec_bih[3 * b + 1]; bi2 = dec_bih[3 * b + 2]; }
  const int rowbase = b * RPB;
  const int nrows = min(RPB, max(0, NV - rowbase));
  const int p = tid >> 1, hf = tid & 1;
  const bool wact = (p < nrows);
  float wa[128];
  {
    const float4* wp = (const float4*)(w_out + (size_t)(rowbase + (wact ? p : 0)) * H + hf * 128);
#pragma unroll
    for (int i = 0; i < 32; ++i) {
      float4 v = wact ? wp[i] : make_float4(0.f, 0.f, 0.f, 0.f);
      agpr_w(wa[4 * i + 0], v.x);
      agpr_w(wa[4 * i + 1], v.y);
      agpr_w(wa[4 * i + 2], v.z);
      agpr_w(wa[4 * i + 3], v.w);
    }
  }
  if (tid < RPB) sh_bout[tid] = (tid < nrows) ? b_out[rowbase + tid] : 0.f;
  const unsigned salt = *(volatile unsigned*)(ws + WS_SALT);
  const unsigned tb32 = salt * 65536u;
  const unsigned tb24 = salt * 4096u;
  __syncthreads();

  auto wave_maxidx = [&](float& mv, int& mi) {
#pragma unroll
    for (int off = 32; off >= 1; off >>= 1) {
      float ov = __shfl_xor(mv, off);
      int oi = __shfl_xor(mi, off);
      if (ov > mv || (ov == mv && oi < mi)) { mv = ov; mi = oi; }
    }
  };
  auto row3 = [&](const float(&wr)[3][H], float bb0, float bb1, float bb2, const float* vin) {
    int q = tid >> 7, i = tid & 127;
    float pp = 0.f;
    if (q < 3) pp = wr[q][2 * i] * vin[2 * i] + wr[q][2 * i + 1] * vin[2 * i + 1];
#pragma unroll
    for (int off = 32; off >= 1; off >>= 1) pp += __shfl_xor(pp, off);
    if (q < 3 && (tid & 63) == 0) sh_rv[tid >> 6] = pp;
    __syncthreads();
    if (tid == 0) {
      sh_gh3[0] = sh_rv[0] + sh_rv[1] + bb0;
      sh_gh3[1] = sh_rv[2] + sh_rv[3] + bb1;
      sh_gh3[2] = sh_rv[4] + sh_rv[5] + bb2;
    }
    __syncthreads();
  };
  auto spin_rec3 = [&](unsigned tg, float* dst) {
    if (tid < NBLK) {
      u64* pp_ = rec + (size_t)(tg & 1) * 1024 + (size_t)tid * 4;
      u64 w0 = 0, w1 = 0, w2 = 0; int n = 0; bool ok;
      do {
        w0 = ard(pp_ + 0); w1 = ard(pp_ + 1); w2 = ard(pp_ + 2);
        ok = (tagof(w0) == tg) & (tagof(w1) == tg) & (tagof(w2) == tg);
      } while (!ok && ++n < SPIN_LIM);
      if (!ok) sh_abort = 1;
      dst[3 * tid] = upf(w0); dst[3 * tid + 1] = upf(w1); dst[3 * tid + 2] = upf(w2);
    }
    __syncthreads();
  };

  // ---- gather h_enc ----
  if (tid < NBLK) {
    u64* pp_ = henc + tid;
    u64 w = 0; int n_ = 0;
    do { w = ard(pp_); } while (tagof(w) != tb32 + (unsigned)TSEQ && ++n_ < SPIN_LIM);
    if (tagof(w) != tb32 + (unsigned)TSEQ) sh_abort = 1;
    sh_h[tid] = upf(w);
  }
  __syncthreads();
  if (sh_abort) return;

  int e = TSEQ;
  // ---- bridge ----
  row3(sh_wd, bd0, bd1, bd2, sh_h);
  ++e;
  {
    unsigned tg = tb32 + (unsigned)e;
    if (tid == 0) {
      u64* d = rec + (size_t)(tg & 1) * 1024 + (size_t)b * 4;
      awr(d + 0, pkf(tg, sh_gh3[0]));
      awr(d + 1, pkf(tg, sh_gh3[1]));
      awr(d + 2, pkf(tg, sh_gh3[2]));
    }
    spin_rec3(tg, gh_lds);
    if (sh_abort) return;
  }

  int tok = SOS_TOK;
  float g0 = 0.f, g1 = 0.f, g2 = 0.f;   // per-thread gi registers (tid<256, table path)
  if (use_table) {
    if (tid < H) {
      const float* tr = table + (size_t)SOS_TOK * H3;
      g0 = tr[tid]; g1 = tr[H + tid]; g2 = tr[2 * H + tid];
    }
  } else {
    for (int j = tid; j < H; j += NTHR) sh_e[j] = fmaxf(dec_emb[(size_t)SOS_TOK * H + j], 0.f);
    __syncthreads();
    row3(sh_wi, bi0, bi1, bi2, sh_e);
    ++e;
    unsigned tg = tb32 + (unsigned)e;
    if (tid == 0) {
      u64* d = rec + (size_t)(tg & 1) * 1024 + (size_t)b * 4;
      awr(d + 0, pkf(tg, sh_gh3[0]));
      awr(d + 1, pkf(tg, sh_gh3[1]));
      awr(d + 2, pkf(tg, sh_gh3[2]));
    }
    spin_rec3(tg, sh_gi);
    if (sh_abort) return;
  }

  const int wv = tid >> 6, ln = tid & 63;
  float sv_p = 0.f, bm_p = -INFINITY, gm_p = 0.f;
  for (int t = 0; t < TSEQ; ++t) {
    const int cur = t & 1;
    // B: gru — gi from registers (table) or sh_gi (exchange); no pre-barrier needed
    if (tid < H) {
      float gir, giz, gin;
      if (use_table) { gir = g0; giz = g1; gin = g2; }
      else { gir = sh_gi[tid]; giz = sh_gi[H + tid]; gin = sh_gi[2 * H + tid]; }
      float ghr = gh_lds[tid], ghz = gh_lds[H + tid], ghn = gh_lds[2 * H + tid];
      float r = 1.f / (1.f + expf(-(gir + ghr)));
      float z = 1.f / (1.f + expf(-(giz + ghz)));
      float n = tanhf(gin + r * ghn);
      sh_h[tid] = (1.f - z) * n + z * sh_h[tid];
    }
    __syncthreads();                      // barrier 1: sh_h committed
    // C: logits + register wave-max (one barrier commits sh_lg AND sh_mv)
    float acc = 0.f;
    if (wact) {
      const float4* h4 = ((const float4*)sh_h) + hf * 32;
#pragma unroll
      for (int i = 0; i < 32; ++i) {
        float4 hv = h4[i];
        acc += agpr_r(wa[4 * i + 0]) * hv.x + agpr_r(wa[4 * i + 1]) * hv.y +
               agpr_r(wa[4 * i + 2]) * hv.z + agpr_r(wa[4 * i + 3]) * hv.w;
      }
    }
    acc += __shfl_xor(acc, 1);
    float lgv = acc + ((wact && hf == 0) ? sh_bout[p] : 0.f);
    if (wact && hf == 0) sh_lg[cur][p] = lgv;
    float mv = (wact && hf == 0) ? lgv : -INFINITY;
    int mi = (wact && hf == 0) ? (rowbase + p) : 0x7fffffff;
    wave_maxidx(mv, mi);
    if (ln == 0) { sh_mv[wv] = mv; sh_mi[wv] = mi; }
    __syncthreads();                      // barrier 2: sh_lg + sh_mv committed
    ++e;
    const unsigned tg32 = tb32 + (unsigned)e;
    const unsigned tg24 = (tb24 + (unsigned)e) & 0xFFFFFFu;
    // D: 8-way merge -> gate publish FIRST
    float bmax = sh_mv[0]; int bidx = sh_mi[0];
#pragma unroll
    for (int k = 1; k < 8; ++k)
      if (sh_mv[k] > bmax || (sh_mv[k] == bmax && sh_mi[k] < bidx)) { bmax = sh_mv[k]; bidx = sh_mi[k]; }
    if (tid == 0) {
      u64 g = ((u64)tg24 << 40) | ((u64)__float_as_uint(bmax) << 8) |
              (u64)((unsigned)(bidx - rowbase) & 0xFFu);
      awr(pmx + (size_t)(e & 1) * 256 + b, g);
    }
    // E: wave-parallel production, barrier-free
    if (wv < 3) {
      float pp = 0.f;
      const float* wr = sh_wd[wv];
      int c0 = 4 * ln;
#pragma unroll
      for (int j = 0; j < 4; ++j) pp += wr[c0 + j] * sh_h[c0 + j];
#pragma unroll
      for (int off = 32; off >= 1; off >>= 1) pp += __shfl_xor(pp, off);
      if (ln == 0) {
        float bb = (wv == 0) ? bd0 : ((wv == 1) ? bd1 : bd2);
        awr(rec + (size_t)(e & 1) * 1024 + (size_t)b * 4 + wv, pkf(tg32, pp + bb));
      }
    } else if (wv == 3) {
      float s = 0.f;
#pragma unroll
      for (int j = 0; j < 4; ++j) {
        int r2 = ln + 64 * j;
        if (r2 < nrows) s += __expf(sh_lg[cur][r2] - bmax);
      }
#pragma unroll
      for (int off = 32; off >= 1; off >>= 1) s += __shfl_xor(s, off);
      if (ln == 0)
        awr(rec + (size_t)(e & 1) * 1024 + (size_t)b * 4 + 3, pkf(tg32, s));
    }
    // F: deferred lse(t-1) + out row t-1 (absorbed by publish->detect slack)
    if (t > 0) {
      float c = (tid < NBLK) ? sv_p * __expf(bm_p - gm_p) : 0.f;
#pragma unroll
      for (int off = 32; off >= 1; off >>= 1) c += __shfl_xor(c, off);
      if (ln == 0) sh_sv2[wv] = c;
      __syncthreads();                    // barrier 3
      float S = 0.f;
#pragma unroll
      for (int k = 0; k < 8; ++k) S += sh_sv2[k];
      float lse = gm_p + logf(S);
      if (tid < nrows)
        out[(size_t)(t - 1) * NV + rowbase + tid] = sh_lg[cur ^ 1][tid] - lse;
    }
    // G: sequential gate spin
    float bm_e = -INFINITY; int ie = 0x7fffffff;
    {
      u64 w = 0;
      if (tid < NBLK) {
        u64* pp_ = pmx + (size_t)(e & 1) * 256 + tid;
        int n = 0;
        do { w = ard(pp_); } while ((unsigned)(w >> 40) != tg24 && ++n < SPIN_LIM);
        if ((unsigned)(w >> 40) != tg24) sh_abort = 1;
        bm_e = __uint_as_float((unsigned)((w >> 8) & 0xFFFFFFFFu));
        ie = tid * RPB + (int)(w & 0xFFu);
      }
      __syncthreads();                    // barrier 4
      if (sh_abort) return;
    }
    // merge argmax -> tok
    float mv2 = bm_e; int mi2 = ie;
    wave_maxidx(mv2, mi2);
    if (ln == 0) { sh_mv2[wv] = mv2; sh_mi2[wv] = mi2; }
    __syncthreads();                      // barrier 5
    float gmax = sh_mv2[0]; int gidx = sh_mi2[0];
#pragma unroll
    for (int k = 1; k < 8; ++k)
      if (sh_mv2[k] > gmax || (sh_mv2[k] == gmax && sh_mi2[k] < gidx)) { gmax = sh_mv2[k]; gidx = sh_mi2[k]; }
    tok = gidx;
    // issue next token's gi register loads (latency hidden under rec gather)
    if (use_table && t + 1 < TSEQ && tid < H) {
      const float* tr = table + (size_t)tok * H3;
      g0 = tr[tid]; g1 = tr[H + tid]; g2 = tr[2 * H + tid];
    }
    // H: one-shot rec gather (published early in E -> usually first-try)
    float sv = 0.f;
    if (tid < NBLK) {
      u64* pp_ = rec + (size_t)(e & 1) * 1024 + (size_t)tid * 4;
      u64 w0 = 0, w1 = 0, w2 = 0, w3 = 0; int n = 0; bool ok;
      do {
        w0 = ard(pp_ + 0); w1 = ard(pp_ + 1); w2 = ard(pp_ + 2); w3 = ard(pp_ + 3);
        ok = (tagof(w0) == tg32) & (tagof(w1) == tg32) & (tagof(w2) == tg32) &
             (tagof(w3) == tg32);
      } while (!ok && ++n < SPIN_LIM);
      if (!ok) sh_abort = 1;
      gh_lds[3 * tid] = upf(w0); gh_lds[3 * tid + 1] = upf(w1); gh_lds[3 * tid + 2] = upf(w2);
      sv = upf(w3);
    }
    __syncthreads();                      // barrier 6
    if (sh_abort) return;
    sv_p = sv; bm_p = bm_e; gm_p = gmax;
    // !use_table: full gi exchange for next token
    if (!use_table && t + 1 < TSEQ) {
      for (int j = tid; j < H; j += NTHR) sh_e[j] = fmaxf(dec_emb[(size_t)tok * H + j], 0.f);
      __syncthreads();
      row3(sh_wi, bi0, bi1, bi2, sh_e);
      ++e;
      unsigned tgg = tb32 + (unsigned)e;
      if (tid == 0) {
        u64* d = rec + (size_t)(tgg & 1) * 1024 + (size_t)b * 4;
        awr(d + 0, pkf(tgg, sh_gh3[0]));
        awr(d + 1, pkf(tgg, sh_gh3[1]));
        awr(d + 2, pkf(tgg, sh_gh3[2]));
      }
      spin_rec3(tgg, sh_gi);
      if (sh_abort) return;
    }
  }
  // epilogue: lse + final row
  {
    float c = (tid < NBLK) ? sv_p * __expf(bm_p - gm_p) : 0.f;
#pragma unroll
    for (int off = 32; off >= 1; off >>= 1) c += __shfl_xor(c, off);
    if (ln == 0) sh_sv2[wv] = c;
    __syncthreads();
    float S = 0.f;
#pragma unroll
    for (int k = 0; k < 8; ++k) S += sh_sv2[k];
    float lse = gm_p + logf(S);
    if (tid < nrows)
      out[(size_t)(TSEQ - 1) * NV + rowbase + tid] = sh_lg[(TSEQ - 1) & 1][tid] - lse;
  }
}

extern "C" void kernel_launch(void* const* d_in, const int* in_sizes, int n_in,
                              void* d_out, int out_size, void* d_ws, size_t ws_size,
                              hipStream_t stream) {
  (void)in_sizes; (void)n_in; (void)out_size;
  const int* x = (const int*)d_in[0];
  const float* enc_emb = (const float*)d_in[1];
  const float* enc_wih = (const float*)d_in[2];
  const float* enc_whh = (const float*)d_in[3];
  const float* enc_bih = (const float*)d_in[4];
  const float* enc_bhh = (const float*)d_in[5];
  const float* dec_emb = (const float*)d_in[6];
  const float* dec_wih = (const float*)d_in[7];
  const float* dec_whh = (const float*)d_in[8];
  const float* dec_bih = (const float*)d_in[9];
  const float* dec_bhh = (const float*)d_in[10];
  const float* w_out = (const float*)d_in[11];
  const float* b_out = (const float*)d_in[12];
  float* out = (float*)d_out;
  char* ws = (char*)d_ws;

  int use_table = (ws_size >= (size_t)WS_TABLE + TABLE_BYTES) ? 1 : 0;

  k_init<<<1, 64, 0, stream>>>(ws);
  k_enc_gi<<<TSEQ / 16, 256, 0, stream>>>(x, enc_emb, enc_wih, enc_bih, (float*)(ws + WS_GIENC));
  k_enc<<<NEB_L, NTHR, 0, stream>>>(enc_whh, enc_bhh, dec_emb, dec_wih, dec_bih, ws, use_table);
  k_dec<<<NBLK, NTHR, 0, stream>>>(dec_emb, dec_wih, dec_whh, dec_bih, dec_bhh,
                                   w_out, b_out, out, ws, use_table);
}